// Round 9
// baseline (635.966 us; speedup 1.0000x reference)
//
#include <hip/hip_runtime.h>
#include <hip/hip_bf16.h>
#include <cstdint>
#include <cstddef>

// SNN: B=16384, D_IN=512, H0=1024, H1=512, T=8
// out[i] = b3 + (1/8) * sum_n w3[n] * popcount(spk2_pattern[i][n])
//
// NUMERICS FROZEN at the round-3 passing configuration (absmax 3.234863e-3):
//  - K1: f32 VALU GEMM, per-element fmaf chain in strict k=0..511 order.
//  - K2: MFMA, A = spike bits -> bf16 {0,1} via v_perm, B = w2 pre-split
//        hi/mid/lo bf16, 3 MFMAs/frag in hi,mid,lo order, s->t->nf order.
// The absmax gate is a spike-flip lottery (threshold < max|w3|/8): any
// numeric deviation re-rolls the dice. Structure-only changes allowed.
//
// Round 9 structure changes (bit-exact):
//  - K2: REVERT round-8 t-split (bank conflicts doubled, no occupancy gain).
//    Back to 256 thr / 4 waves / acc[8][4], dbuf + async-stage (round 7).
//  - K2: FRAGMENT-ORDER LDS. B splits stored [cur][s][nf][lane][8 bf16],
//    Ap stored [cur][s][ig][lane][8 u8] -> every wave read is base+lane*16
//    (bandwidth floor, no bank conflicts). Round-7 stride-72 layout had
//    8-start-bank aliasing = 14.7M conflict cycles.
//  - K1: register prefetch of next k-tile (8 float4/thread) issued right
//    after the barrier, written to LDS next iteration -> global latency
//    hides under the 4096-cyc FMA block instead of stalling the barrier.

#define NB 16384
#define DIN 512
#define NH0 1024
#define NH1 512

typedef float f32x4 __attribute__((ext_vector_type(4)));
typedef short bf16x8 __attribute__((ext_vector_type(8)));

// d_ws layout (bytes)
#define WS_PAT   0u
#define WS_W2H   19922944u
#define WS_W2M   20971520u
#define WS_W2L   22020096u

__device__ inline uint16_t f2bf(float f) {
    __hip_bfloat16 h = __float2bfloat16(f);
    return *reinterpret_cast<uint16_t*>(&h);
}
__device__ inline float bf2f(uint16_t u) {
    __hip_bfloat16 h = *reinterpret_cast<__hip_bfloat16*>(&u);
    return __bfloat162float(h);
}

__global__ void init_out_kernel(float* __restrict__ out,
                                const float* __restrict__ b3, int n) {
    int i = blockIdx.x * blockDim.x + threadIdx.x;
    if (i < n) out[i] = b3[0];
}

// ---------------- split3: f32 -> bf16 hi/mid/lo (elementwise) ----------------
__global__ __launch_bounds__(256) void split3_kernel(
    const float* __restrict__ src, uint16_t* __restrict__ h,
    uint16_t* __restrict__ m, uint16_t* __restrict__ l, int n)
{
    int i = (blockIdx.x * 256 + threadIdx.x) * 4;
    if (i >= n) return;
    float4 f = *(const float4*)(src + i);
    float fv[4] = {f.x, f.y, f.z, f.w};
    uint32_t hw[2], mw[2], lw[2];
    #pragma unroll
    for (int g = 0; g < 2; ++g) {
        uint16_t hh[2], mm[2], ll[2];
        #pragma unroll
        for (int e = 0; e < 2; ++e) {
            float a = fv[2 * g + e];
            uint16_t h0 = f2bf(a);
            float d = __fsub_rn(a, bf2f(h0));
            uint16_t m0 = f2bf(d);
            float e2 = __fsub_rn(d, bf2f(m0));
            uint16_t l0 = f2bf(e2);
            hh[e] = h0; mm[e] = m0; ll[e] = l0;
        }
        hw[g] = (uint32_t)hh[0] | ((uint32_t)hh[1] << 16);
        mw[g] = (uint32_t)mm[0] | ((uint32_t)mm[1] << 16);
        lw[g] = (uint32_t)ll[0] | ((uint32_t)ll[1] << 16);
    }
    *(uint2*)(h + i) = make_uint2(hw[0], hw[1]);
    *(uint2*)(m + i) = make_uint2(mw[0], mw[1]);
    *(uint2*)(l + i) = make_uint2(lw[0], lw[1]);
}

// - K1: f32 VALU GEMM1 + LIF1, 512 thr, 128x128, 8x4/thread, reg-prefetch -
__global__ __launch_bounds__(512, 4) void gemm1_spike_kernel(
    const float* __restrict__ data, const float* __restrict__ w1,
    const float* __restrict__ b1, uint8_t* __restrict__ pat)
{
    __shared__ float As[128][68];
    __shared__ float Bs[128][68];
    const int tid = threadIdx.x;
    const int tx = tid & 31;
    const int ty = tid >> 5;
    const int i0 = blockIdx.x * 128, n0 = blockIdx.y * 128;

    float acc[8][4] = {};
    float4 pa[4], pb[4];

    // prologue: prefetch tile 0 into registers
    #pragma unroll
    for (int rep = 0; rep < 4; ++rep) {
        int idx = tid + rep * 512;
        int row = idx >> 4, c4 = (idx & 15) * 4;
        pa[rep] = *(const float4*)(data + (size_t)(i0 + row) * DIN + c4);
        pb[rep] = *(const float4*)(w1 + (size_t)(n0 + row) * DIN + c4);
    }

    for (int kb = 0; kb < DIN; kb += 64) {
        // write prefetched tile to LDS
        #pragma unroll
        for (int rep = 0; rep < 4; ++rep) {
            int idx = tid + rep * 512;
            int row = idx >> 4, c4 = (idx & 15) * 4;
            *(float4*)(&As[row][c4]) = pa[rep];
            *(float4*)(&Bs[row][c4]) = pb[rep];
        }
        __syncthreads();
        // issue next tile's loads (complete during the FMA block below)
        if (kb + 64 < DIN) {
            #pragma unroll
            for (int rep = 0; rep < 4; ++rep) {
                int idx = tid + rep * 512;
                int row = idx >> 4, c4 = (idx & 15) * 4;
                pa[rep] = *(const float4*)(data + (size_t)(i0 + row) * DIN + kb + 64 + c4);
                pb[rep] = *(const float4*)(w1 + (size_t)(n0 + row) * DIN + kb + 64 + c4);
            }
        }
        #pragma unroll 2
        for (int k4 = 0; k4 < 16; ++k4) {
            float4 a4[8], b4[4];
            #pragma unroll
            for (int ii = 0; ii < 8; ++ii)
                a4[ii] = *(const float4*)(&As[ty + ii * 16][k4 * 4]);
            #pragma unroll
            for (int nn = 0; nn < 4; ++nn)
                b4[nn] = *(const float4*)(&Bs[tx + nn * 32][k4 * 4]);
            #pragma unroll
            for (int ii = 0; ii < 8; ++ii) {
                #pragma unroll
                for (int nn = 0; nn < 4; ++nn) {
                    acc[ii][nn] = fmaf(a4[ii].x, b4[nn].x, acc[ii][nn]);
                    acc[ii][nn] = fmaf(a4[ii].y, b4[nn].y, acc[ii][nn]);
                    acc[ii][nn] = fmaf(a4[ii].z, b4[nn].z, acc[ii][nn]);
                    acc[ii][nn] = fmaf(a4[ii].w, b4[nn].w, acc[ii][nn]);
                }
            }
        }
        __syncthreads();
    }

    // LIF1 (bit-identical chain) -> blocked pat2[n>>6][i][n&63]
    #pragma unroll
    for (int ii = 0; ii < 8; ++ii) {
        const int i = i0 + ty + ii * 16;
        #pragma unroll
        for (int nn = 0; nn < 4; ++nn) {
            const int n = n0 + tx + nn * 32;
            float x = __fadd_rn(acc[ii][nn], b1[n]);
            float mem = 0.0f;
            unsigned p = 0;
            #pragma unroll
            for (int t = 0; t < 8; ++t) {
                bool reset = mem > 1.0f;
                float tmp = __fadd_rn(mem, x);
                mem = reset ? __fsub_rn(tmp, 1.0f) : tmp;
                p |= (mem > 1.0f ? 1u : 0u) << t;
            }
            pat[(size_t)(n >> 6) * (NB * 64) + (size_t)i * 64 + (n & 63)] = (uint8_t)p;
        }
    }
}

// -- K2: MFMA 8x GEMM, fragment-order LDS (conflict-free), dbuf, 1 barrier --
__global__ __launch_bounds__(256, 2) void gemm2_mfma_kernel(
    const uint8_t* __restrict__ pat,
    const uint16_t* __restrict__ w2h, const uint16_t* __restrict__ w2m,
    const uint16_t* __restrict__ w2l,
    const float* __restrict__ b2, const float* __restrict__ w3,
    float* __restrict__ out)
{
    // fragment order: Bx_[cur*4096 + ((s*4+nf)*64 + lane)*8] (u16)
    //                 Ap_[cur*4096 + ((s*4+ig)*64 + lane)*8] (u8)
    __shared__ __align__(16) uint16_t Bh_[8192];
    __shared__ __align__(16) uint16_t Bm_[8192];
    __shared__ __align__(16) uint16_t Bl_[8192];
    __shared__ __align__(16) uint8_t  Ap_[8192];

    const int tid  = threadIdx.x;
    const int lane = tid & 63;
    const int wv   = tid >> 6;       // i-row group 0..3
    const int lr   = lane & 15;
    const int lg   = lane >> 4;
    const int i0   = blockIdx.x * 64, n0 = blockIdx.y * 64;

    f32x4 acc[8][4];
    #pragma unroll
    for (int t = 0; t < 8; ++t)
        #pragma unroll
        for (int nf = 0; nf < 4; ++nf)
            acc[t][nf] = (f32x4)(0.0f);

    // staging: thread -> (row c = tid>>2, k-chunk (tid&3)*16), two 8-elem halves
    const int srow = tid >> 2;
    const int scol = (tid & 3) * 16;
    const size_t wbase = (size_t)(n0 + srow) * NH0 + scol;
    const size_t pbase = (size_t)i0 * 64 + (size_t)tid * 16;
    // fragment-order write slots (same index math for B in u16 and Ap in u8)
    const int nf_w  = srow >> 4, lr_w = srow & 15;
    const int ub0 = (((scol >> 5)       * 4 + nf_w) * 64 + ((scol >> 3) & 3)       * 16 + lr_w) * 8;
    const int ub1 = ((((scol + 8) >> 5) * 4 + nf_w) * 64 + (((scol + 8) >> 3) & 3) * 16 + lr_w) * 8;

    uint4 rh0, rh1, rm0, rm1, rl0, rl1, rp;

#define K2_LOAD(kt) do { \
        const size_t o = wbase + (size_t)(kt) * 64; \
        rh0 = *(const uint4*)(w2h + o); rh1 = *(const uint4*)(w2h + o + 8); \
        rm0 = *(const uint4*)(w2m + o); rm1 = *(const uint4*)(w2m + o + 8); \
        rl0 = *(const uint4*)(w2l + o); rl1 = *(const uint4*)(w2l + o + 8); \
        rp  = *(const uint4*)(pat + (size_t)(kt) * (NB * 64) + pbase); \
    } while (0)

#define K2_WRITE(nb) do { \
        *(uint4*)(Bh_ + (nb) * 4096 + ub0) = rh0; *(uint4*)(Bh_ + (nb) * 4096 + ub1) = rh1; \
        *(uint4*)(Bm_ + (nb) * 4096 + ub0) = rm0; *(uint4*)(Bm_ + (nb) * 4096 + ub1) = rm1; \
        *(uint4*)(Bl_ + (nb) * 4096 + ub0) = rl0; *(uint4*)(Bl_ + (nb) * 4096 + ub1) = rl1; \
        *(uint2*)(Ap_ + (nb) * 4096 + ub0) = make_uint2(rp.x, rp.y); \
        *(uint2*)(Ap_ + (nb) * 4096 + ub1) = make_uint2(rp.z, rp.w); \
    } while (0)

    // prologue: stage tile 0 into buffer 0
    K2_LOAD(0);
    K2_WRITE(0);

    int cur = 0;
    for (int kbi = 0; kbi < 16; ++kbi) {
        __syncthreads();   // buf[cur] ready; buf[cur^1] free
        if (kbi < 15) K2_LOAD(kbi + 1);

        // ---- compute tile kbi from buf[cur] (MFMA order frozen) ----
        #pragma unroll
        for (int s = 0; s < 2; ++s) {
            bf16x8 bh[4], bm[4], bl[4];
            #pragma unroll
            for (int nf = 0; nf < 4; ++nf) {
                const int fo = cur * 4096 + ((s * 4 + nf) * 64 + lane) * 8;
                bh[nf] = *(const bf16x8*)(Bh_ + fo);
                bm[nf] = *(const bf16x8*)(Bm_ + fo);
                bl[nf] = *(const bf16x8*)(Bl_ + fo);
            }
            const uint2 p8 = *(const uint2*)(Ap_ + cur * 4096 +
                                             ((s * 4 + wv) * 64 + lane) * 8);
            #pragma unroll
            for (int t = 0; t < 8; ++t) {
                uint32_t y0 = (p8.x >> t) & 0x01010101u;
                uint32_t y1 = (p8.y >> t) & 0x01010101u;
                uint32_t s0 = __builtin_amdgcn_perm(0u, y0, 0x01010000u) | 0x02000200u;
                uint32_t s1x = __builtin_amdgcn_perm(0u, y0, 0x03030202u) | 0x02000200u;
                uint32_t s2x = __builtin_amdgcn_perm(0u, y1, 0x01010000u) | 0x02000200u;
                uint32_t s3x = __builtin_amdgcn_perm(0u, y1, 0x03030202u) | 0x02000200u;
                union { uint4 u; bf16x8 v; } af;
                af.u = make_uint4(__builtin_amdgcn_perm(0u, 0x3F008000u, s0),
                                  __builtin_amdgcn_perm(0u, 0x3F008000u, s1x),
                                  __builtin_amdgcn_perm(0u, 0x3F008000u, s2x),
                                  __builtin_amdgcn_perm(0u, 0x3F008000u, s3x));
                #pragma unroll
                for (int nf = 0; nf < 4; ++nf) {
                    acc[t][nf] = __builtin_amdgcn_mfma_f32_16x16x32_bf16(
                        af.v, bh[nf], acc[t][nf], 0, 0, 0);
                    acc[t][nf] = __builtin_amdgcn_mfma_f32_16x16x32_bf16(
                        af.v, bm[nf], acc[t][nf], 0, 0, 0);
                    acc[t][nf] = __builtin_amdgcn_mfma_f32_16x16x32_bf16(
                        af.v, bl[nf], acc[t][nf], 0, 0, 0);
                }
            }
        }

        if (kbi < 15) K2_WRITE(cur ^ 1);
        cur ^= 1;
    }

    // LIF2 + popcount*w3 (bit-identical to round 3)
    float rowsum[4] = {0.0f, 0.0f, 0.0f, 0.0f};
    #pragma unroll
    for (int nf = 0; nf < 4; ++nf) {
        const int n = n0 + nf * 16 + lr;
        const float b2n = b2[n];
        const float w3n = w3[n];
        #pragma unroll
        for (int r = 0; r < 4; ++r) {
            float mem = 0.0f;
            int pc = 0;
            #pragma unroll
            for (int t = 0; t < 8; ++t) {
                bool reset = mem > 1.0f;
                float x   = __fadd_rn(acc[t][nf][r], b2n);
                float tmp = __fadd_rn(__fmul_rn(0.95f, mem), x);
                mem = reset ? __fsub_rn(tmp, 1.0f) : tmp;
                pc += (mem > 1.0f) ? 1 : 0;
            }
            rowsum[r] = fmaf(w3n, (float)pc, rowsum[r]);
        }
    }
    #pragma unroll
    for (int r = 0; r < 4; ++r) {
        float s = rowsum[r];
        s += __shfl_xor(s, 1);
        s += __shfl_xor(s, 2);
        s += __shfl_xor(s, 4);
        s += __shfl_xor(s, 8);
        if (lr == 0)
            atomicAdd(&out[i0 + wv * 16 + lg * 4 + r], 0.125f * s);
    }
}

extern "C" void kernel_launch(void* const* d_in, const int* in_sizes, int n_in,
                              void* d_out, int out_size, void* d_ws, size_t ws_size,
                              hipStream_t stream) {
    const float* data = (const float*)d_in[0];
    const float* w1   = (const float*)d_in[1];
    const float* b1   = (const float*)d_in[2];
    const float* w2   = (const float*)d_in[3];
    const float* b2   = (const float*)d_in[4];
    const float* w3   = (const float*)d_in[5];
    const float* b3   = (const float*)d_in[6];
    float* out = (float*)d_out;

    char* ws = (char*)d_ws;
    uint8_t*  pat = (uint8_t*)(ws + WS_PAT);   // blocked [16][16384][64]
    uint16_t* w2h = (uint16_t*)(ws + WS_W2H);
    uint16_t* w2m = (uint16_t*)(ws + WS_W2M);
    uint16_t* w2l = (uint16_t*)(ws + WS_W2L);

    init_out_kernel<<<(NB + 255) / 256, 256, 0, stream>>>(out, b3, NB);
    split3_kernel<<<(NH1 * NH0 / 4 + 255) / 256, 256, 0, stream>>>(w2, w2h, w2m, w2l, NH1 * NH0);
    gemm1_spike_kernel<<<dim3(NB / 128, NH0 / 128), 512, 0, stream>>>(data, w1, b1, pat);
    gemm2_mfma_kernel<<<dim3(NB / 64, NH1 / 64), 256, 0, stream>>>(pat, w2h, w2m, w2l, b2, w3, out);
}

// Round 11
// 549.585 us; speedup vs baseline: 1.1572x; 1.1572x over previous
//
#include <hip/hip_runtime.h>
#include <hip/hip_bf16.h>
#include <cstdint>
#include <cstddef>

// SNN: B=16384, D_IN=512, H0=1024, H1=512, T=8
// out[i] = b3 + (1/8) * sum_n w3[n] * popcount(spk2_pattern[i][n])
//
// NUMERICS FROZEN at the round-3 passing configuration (absmax 3.234863e-3):
//  - K1: f32 VALU GEMM, per-element fmaf chain in strict k=0..511 order.
//  - K2: MFMA, per-acc op order fixed: for each k64 tile (ascending), s=0,1;
//    within s: hi then mid then lo into acc[t][nf]. Any schedule preserving
//    this per-acc order is bit-exact.
// The absmax gate is a spike-flip lottery (threshold < max|w3|/8): any
// numeric deviation re-rolls the dice. Structure-only changes allowed.
//
// Round 11 = round 10 resubmitted verbatim (round-10 bench was an infra
// failure: container acquisition, no kernel signal).
//  - K1: REVERT round-9 register prefetch (compiler picked 64 VGPR and
//    spilled 521 MB/dispatch of scratch). Exact round-7/8 kernel.
//  - K2: keep fragment-order LDS; reorder MFMA issue into h/m/l PASSES over
//    t-pairs (8 independent accs between dependent MFMAs, was 1) to kill
//    dependent-MFMA latency stalls at 2 waves/SIMD. Bit-exact (per-acc
//    order unchanged).

#define NB 16384
#define DIN 512
#define NH0 1024
#define NH1 512

typedef float f32x4 __attribute__((ext_vector_type(4)));
typedef short bf16x8 __attribute__((ext_vector_type(8)));

// d_ws layout (bytes)
#define WS_PAT   0u
#define WS_W2H   19922944u
#define WS_W2M   20971520u
#define WS_W2L   22020096u

__device__ inline uint16_t f2bf(float f) {
    __hip_bfloat16 h = __float2bfloat16(f);
    return *reinterpret_cast<uint16_t*>(&h);
}
__device__ inline float bf2f(uint16_t u) {
    __hip_bfloat16 h = *reinterpret_cast<__hip_bfloat16*>(&u);
    return __bfloat162float(h);
}

__global__ void init_out_kernel(float* __restrict__ out,
                                const float* __restrict__ b3, int n) {
    int i = blockIdx.x * blockDim.x + threadIdx.x;
    if (i < n) out[i] = b3[0];
}

// ---------------- split3: f32 -> bf16 hi/mid/lo (elementwise) ----------------
__global__ __launch_bounds__(256) void split3_kernel(
    const float* __restrict__ src, uint16_t* __restrict__ h,
    uint16_t* __restrict__ m, uint16_t* __restrict__ l, int n)
{
    int i = (blockIdx.x * 256 + threadIdx.x) * 4;
    if (i >= n) return;
    float4 f = *(const float4*)(src + i);
    float fv[4] = {f.x, f.y, f.z, f.w};
    uint32_t hw[2], mw[2], lw[2];
    #pragma unroll
    for (int g = 0; g < 2; ++g) {
        uint16_t hh[2], mm[2], ll[2];
        #pragma unroll
        for (int e = 0; e < 2; ++e) {
            float a = fv[2 * g + e];
            uint16_t h0 = f2bf(a);
            float d = __fsub_rn(a, bf2f(h0));
            uint16_t m0 = f2bf(d);
            float e2 = __fsub_rn(d, bf2f(m0));
            uint16_t l0 = f2bf(e2);
            hh[e] = h0; mm[e] = m0; ll[e] = l0;
        }
        hw[g] = (uint32_t)hh[0] | ((uint32_t)hh[1] << 16);
        mw[g] = (uint32_t)mm[0] | ((uint32_t)mm[1] << 16);
        lw[g] = (uint32_t)ll[0] | ((uint32_t)ll[1] << 16);
    }
    *(uint2*)(h + i) = make_uint2(hw[0], hw[1]);
    *(uint2*)(m + i) = make_uint2(mw[0], mw[1]);
    *(uint2*)(l + i) = make_uint2(lw[0], lw[1]);
}

// - K1: f32 VALU GEMM1 + LIF1, 512 thr, 128x128 tile, 8x4/thread, bit-exact -
// (exact round-7/8 kernel; round-9's reg-prefetch variant spilled)
__global__ __launch_bounds__(512, 4) void gemm1_spike_kernel(
    const float* __restrict__ data, const float* __restrict__ w1,
    const float* __restrict__ b1, uint8_t* __restrict__ pat)
{
    __shared__ float As[128][68];
    __shared__ float Bs[128][68];
    const int tid = threadIdx.x;
    const int tx = tid & 31;
    const int ty = tid >> 5;
    const int i0 = blockIdx.x * 128, n0 = blockIdx.y * 128;

    float acc[8][4] = {};

    for (int kb = 0; kb < DIN; kb += 64) {
        #pragma unroll
        for (int rep = 0; rep < 4; ++rep) {
            int idx = tid + rep * 512;
            int row = idx >> 4, c4 = (idx & 15) * 4;
            *(float4*)(&As[row][c4]) =
                *(const float4*)(data + (size_t)(i0 + row) * DIN + kb + c4);
            *(float4*)(&Bs[row][c4]) =
                *(const float4*)(w1 + (size_t)(n0 + row) * DIN + kb + c4);
        }
        __syncthreads();
        #pragma unroll 2
        for (int k4 = 0; k4 < 16; ++k4) {
            float4 a4[8], b4[4];
            #pragma unroll
            for (int ii = 0; ii < 8; ++ii)
                a4[ii] = *(const float4*)(&As[ty + ii * 16][k4 * 4]);
            #pragma unroll
            for (int nn = 0; nn < 4; ++nn)
                b4[nn] = *(const float4*)(&Bs[tx + nn * 32][k4 * 4]);
            #pragma unroll
            for (int ii = 0; ii < 8; ++ii) {
                #pragma unroll
                for (int nn = 0; nn < 4; ++nn) {
                    acc[ii][nn] = fmaf(a4[ii].x, b4[nn].x, acc[ii][nn]);
                    acc[ii][nn] = fmaf(a4[ii].y, b4[nn].y, acc[ii][nn]);
                    acc[ii][nn] = fmaf(a4[ii].z, b4[nn].z, acc[ii][nn]);
                    acc[ii][nn] = fmaf(a4[ii].w, b4[nn].w, acc[ii][nn]);
                }
            }
        }
        __syncthreads();
    }

    #pragma unroll
    for (int ii = 0; ii < 8; ++ii) {
        const int i = i0 + ty + ii * 16;
        #pragma unroll
        for (int nn = 0; nn < 4; ++nn) {
            const int n = n0 + tx + nn * 32;
            float x = __fadd_rn(acc[ii][nn], b1[n]);
            float mem = 0.0f;
            unsigned p = 0;
            #pragma unroll
            for (int t = 0; t < 8; ++t) {
                bool reset = mem > 1.0f;
                float tmp = __fadd_rn(mem, x);
                mem = reset ? __fsub_rn(tmp, 1.0f) : tmp;
                p |= (mem > 1.0f ? 1u : 0u) << t;
            }
            pat[(size_t)(n >> 6) * (NB * 64) + (size_t)i * 64 + (n & 63)] = (uint8_t)p;
        }
    }
}

// -- K2: MFMA 8x GEMM, fragment-order LDS, dbuf, h/m/l pass scheduling ------
__global__ __launch_bounds__(256, 2) void gemm2_mfma_kernel(
    const uint8_t* __restrict__ pat,
    const uint16_t* __restrict__ w2h, const uint16_t* __restrict__ w2m,
    const uint16_t* __restrict__ w2l,
    const float* __restrict__ b2, const float* __restrict__ w3,
    float* __restrict__ out)
{
    // fragment order: Bx_[cur*4096 + ((s*4+nf)*64 + lane)*8] (u16)
    //                 Ap_[cur*4096 + ((s*4+ig)*64 + lane)*8] (u8)
    __shared__ __align__(16) uint16_t Bh_[8192];
    __shared__ __align__(16) uint16_t Bm_[8192];
    __shared__ __align__(16) uint16_t Bl_[8192];
    __shared__ __align__(16) uint8_t  Ap_[8192];

    const int tid  = threadIdx.x;
    const int lane = tid & 63;
    const int wv   = tid >> 6;       // i-row group 0..3
    const int lr   = lane & 15;
    const int lg   = lane >> 4;
    const int i0   = blockIdx.x * 64, n0 = blockIdx.y * 64;

    f32x4 acc[8][4];
    #pragma unroll
    for (int t = 0; t < 8; ++t)
        #pragma unroll
        for (int nf = 0; nf < 4; ++nf)
            acc[t][nf] = (f32x4)(0.0f);

    const int srow = tid >> 2;
    const int scol = (tid & 3) * 16;
    const size_t wbase = (size_t)(n0 + srow) * NH0 + scol;
    const size_t pbase = (size_t)i0 * 64 + (size_t)tid * 16;
    const int nf_w  = srow >> 4, lr_w = srow & 15;
    const int ub0 = (((scol >> 5)       * 4 + nf_w) * 64 + ((scol >> 3) & 3)       * 16 + lr_w) * 8;
    const int ub1 = ((((scol + 8) >> 5) * 4 + nf_w) * 64 + (((scol + 8) >> 3) & 3) * 16 + lr_w) * 8;

    uint4 rh0, rh1, rm0, rm1, rl0, rl1, rp;

#define K2_LOAD(kt) do { \
        const size_t o = wbase + (size_t)(kt) * 64; \
        rh0 = *(const uint4*)(w2h + o); rh1 = *(const uint4*)(w2h + o + 8); \
        rm0 = *(const uint4*)(w2m + o); rm1 = *(const uint4*)(w2m + o + 8); \
        rl0 = *(const uint4*)(w2l + o); rl1 = *(const uint4*)(w2l + o + 8); \
        rp  = *(const uint4*)(pat + (size_t)(kt) * (NB * 64) + pbase); \
    } while (0)

#define K2_WRITE(nb) do { \
        *(uint4*)(Bh_ + (nb) * 4096 + ub0) = rh0; *(uint4*)(Bh_ + (nb) * 4096 + ub1) = rh1; \
        *(uint4*)(Bm_ + (nb) * 4096 + ub0) = rm0; *(uint4*)(Bm_ + (nb) * 4096 + ub1) = rm1; \
        *(uint4*)(Bl_ + (nb) * 4096 + ub0) = rl0; *(uint4*)(Bl_ + (nb) * 4096 + ub1) = rl1; \
        *(uint2*)(Ap_ + (nb) * 4096 + ub0) = make_uint2(rp.x, rp.y); \
        *(uint2*)(Ap_ + (nb) * 4096 + ub1) = make_uint2(rp.z, rp.w); \
    } while (0)

    // expand bit t of the 8 pattern bytes in p8 -> bf16x8 {0,1}
#define K2_EXPAND(af, p8, t) do { \
        uint32_t y0 = ((p8).x >> (t)) & 0x01010101u; \
        uint32_t y1 = ((p8).y >> (t)) & 0x01010101u; \
        uint32_t s0 = __builtin_amdgcn_perm(0u, y0, 0x01010000u) | 0x02000200u; \
        uint32_t s1x = __builtin_amdgcn_perm(0u, y0, 0x03030202u) | 0x02000200u; \
        uint32_t s2x = __builtin_amdgcn_perm(0u, y1, 0x01010000u) | 0x02000200u; \
        uint32_t s3x = __builtin_amdgcn_perm(0u, y1, 0x03030202u) | 0x02000200u; \
        (af).u = make_uint4(__builtin_amdgcn_perm(0u, 0x3F008000u, s0), \
                            __builtin_amdgcn_perm(0u, 0x3F008000u, s1x), \
                            __builtin_amdgcn_perm(0u, 0x3F008000u, s2x), \
                            __builtin_amdgcn_perm(0u, 0x3F008000u, s3x)); \
    } while (0)

    // prologue: stage tile 0 into buffer 0
    K2_LOAD(0);
    K2_WRITE(0);

    int cur = 0;
    for (int kbi = 0; kbi < 16; ++kbi) {
        __syncthreads();   // buf[cur] ready; buf[cur^1] free
        if (kbi < 15) K2_LOAD(kbi + 1);

        // ---- compute tile kbi from buf[cur] ----
        // Per-acc order (frozen): s ascending; within s: hi, mid, lo.
        // Schedule: t in pairs; h-pass over 8 (t,nf) accs, then m, then l
        // -> dependent MFMAs 8 issues apart (ILP for 2-wave occupancy).
        #pragma unroll
        for (int s = 0; s < 2; ++s) {
            bf16x8 bh[4], bm[4], bl[4];
            #pragma unroll
            for (int nf = 0; nf < 4; ++nf) {
                const int fo = cur * 4096 + ((s * 4 + nf) * 64 + lane) * 8;
                bh[nf] = *(const bf16x8*)(Bh_ + fo);
                bm[nf] = *(const bf16x8*)(Bm_ + fo);
                bl[nf] = *(const bf16x8*)(Bl_ + fo);
            }
            const uint2 p8 = *(const uint2*)(Ap_ + cur * 4096 +
                                             ((s * 4 + wv) * 64 + lane) * 8);
            #pragma unroll
            for (int tp = 0; tp < 4; ++tp) {
                const int t0 = tp * 2, t1 = tp * 2 + 1;
                union { uint4 u; bf16x8 v; } af0, af1;
                K2_EXPAND(af0, p8, t0);
                K2_EXPAND(af1, p8, t1);
                #pragma unroll
                for (int nf = 0; nf < 4; ++nf)
                    acc[t0][nf] = __builtin_amdgcn_mfma_f32_16x16x32_bf16(
                        af0.v, bh[nf], acc[t0][nf], 0, 0, 0);
                #pragma unroll
                for (int nf = 0; nf < 4; ++nf)
                    acc[t1][nf] = __builtin_amdgcn_mfma_f32_16x16x32_bf16(
                        af1.v, bh[nf], acc[t1][nf], 0, 0, 0);
                #pragma unroll
                for (int nf = 0; nf < 4; ++nf)
                    acc[t0][nf] = __builtin_amdgcn_mfma_f32_16x16x32_bf16(
                        af0.v, bm[nf], acc[t0][nf], 0, 0, 0);
                #pragma unroll
                for (int nf = 0; nf < 4; ++nf)
                    acc[t1][nf] = __builtin_amdgcn_mfma_f32_16x16x32_bf16(
                        af1.v, bm[nf], acc[t1][nf], 0, 0, 0);
                #pragma unroll
                for (int nf = 0; nf < 4; ++nf)
                    acc[t0][nf] = __builtin_amdgcn_mfma_f32_16x16x32_bf16(
                        af0.v, bl[nf], acc[t0][nf], 0, 0, 0);
                #pragma unroll
                for (int nf = 0; nf < 4; ++nf)
                    acc[t1][nf] = __builtin_amdgcn_mfma_f32_16x16x32_bf16(
                        af1.v, bl[nf], acc[t1][nf], 0, 0, 0);
            }
        }

        if (kbi < 15) K2_WRITE(cur ^ 1);
        cur ^= 1;
    }

    // LIF2 + popcount*w3 (bit-identical to round 3)
    float rowsum[4] = {0.0f, 0.0f, 0.0f, 0.0f};
    #pragma unroll
    for (int nf = 0; nf < 4; ++nf) {
        const int n = n0 + nf * 16 + lr;
        const float b2n = b2[n];
        const float w3n = w3[n];
        #pragma unroll
        for (int r = 0; r < 4; ++r) {
            float mem = 0.0f;
            int pc = 0;
            #pragma unroll
            for (int t = 0; t < 8; ++t) {
                bool reset = mem > 1.0f;
                float x   = __fadd_rn(acc[t][nf][r], b2n);
                float tmp = __fadd_rn(__fmul_rn(0.95f, mem), x);
                mem = reset ? __fsub_rn(tmp, 1.0f) : tmp;
                pc += (mem > 1.0f) ? 1 : 0;
            }
            rowsum[r] = fmaf(w3n, (float)pc, rowsum[r]);
        }
    }
    #pragma unroll
    for (int r = 0; r < 4; ++r) {
        float s = rowsum[r];
        s += __shfl_xor(s, 1);
        s += __shfl_xor(s, 2);
        s += __shfl_xor(s, 4);
        s += __shfl_xor(s, 8);
        if (lr == 0)
            atomicAdd(&out[i0 + wv * 16 + lg * 4 + r], 0.125f * s);
    }
}

extern "C" void kernel_launch(void* const* d_in, const int* in_sizes, int n_in,
                              void* d_out, int out_size, void* d_ws, size_t ws_size,
                              hipStream_t stream) {
    const float* data = (const float*)d_in[0];
    const float* w1   = (const float*)d_in[1];
    const float* b1   = (const float*)d_in[2];
    const float* w2   = (const float*)d_in[3];
    const float* b2   = (const float*)d_in[4];
    const float* w3   = (const float*)d_in[5];
    const float* b3   = (const float*)d_in[6];
    float* out = (float*)d_out;

    char* ws = (char*)d_ws;
    uint8_t*  pat = (uint8_t*)(ws + WS_PAT);   // blocked [16][16384][64]
    uint16_t* w2h = (uint16_t*)(ws + WS_W2H);
    uint16_t* w2m = (uint16_t*)(ws + WS_W2M);
    uint16_t* w2l = (uint16_t*)(ws + WS_W2L);

    init_out_kernel<<<(NB + 255) / 256, 256, 0, stream>>>(out, b3, NB);
    split3_kernel<<<(NH1 * NH0 / 4 + 255) / 256, 256, 0, stream>>>(w2, w2h, w2m, w2l, NH1 * NH0);
    gemm1_spike_kernel<<<dim3(NB / 128, NH0 / 128), 512, 0, stream>>>(data, w1, b1, pat);
    gemm2_mfma_kernel<<<dim3(NB / 64, NH1 / 64), 256, 0, stream>>>(pat, w2h, w2m, w2l, b2, w3, out);
}